// Round 1
// baseline (3579.973 us; speedup 1.0000x reference)
//
#include <hip/hip_runtime.h>
#include <hip/hip_bf16.h>
#include <math.h>

// CrissCrossAttention (height branch), B=8 H=128 W=128 C=512, fp32 in/out.
//
// Algebra: energy = x (Wq^T Wk) x^T per (b,w) column; out = gamma*(attn @ (x Wv^T)) + x.
// K0:  M = Wq^T @ Wk  (512x512 fp32, stored in d_ws -> needs only 1 MB scratch)
// K1:  fused per-column kernel: t = x_col@M, e = t@x_col^T (all fp32 -> softmax
//      sees fp32-exact logits; bf16 logits would be marginal vs the 0.1275
//      threshold), masked softmax in regs, v = x_col@Wv^T and out = attn@v in
//      bf16 LDS tiles (error here is not softmax-amplified). 64 KB LDS exactly,
//      2 blocks/CU.

#define HH 128
#define WW 128
#define CS 512
// h-stride inside x for fixed (b,w): WW*CS
#define HSTRIDE 65536

__global__ void cca_compute_M(const float* __restrict__ Wq,
                              const float* __restrict__ Wk,
                              float* __restrict__ M) {
  __shared__ float Wqs[64 * 17];
  __shared__ float Wks[64 * 17];
  const int tid = threadIdx.x;
  const int ti = tid >> 4;   // 0..15 -> i
  const int tj = tid & 15;   // 0..15 -> j (consecutive lanes -> coalesced M write)
  const int i0 = (blockIdx.x & 31) << 4;
  const int j0 = (blockIdx.x >> 5) << 4;
  float acc = 0.f;
  for (int ac = 0; ac < 8; ++ac) {
    __syncthreads();
#pragma unroll
    for (int s = 0; s < 4; ++s) {
      int idx = tid + 256 * s;
      int r = idx >> 4;
      int c = idx & 15;
      Wqs[r * 17 + c] = Wq[(ac * 64 + r) * 512 + i0 + c];
      Wks[r * 17 + c] = Wk[(ac * 64 + r) * 512 + j0 + c];
    }
    __syncthreads();
#pragma unroll
    for (int r = 0; r < 64; ++r)
      acc = fmaf(Wqs[r * 17 + ti], Wks[r * 17 + tj], acc);
  }
  // M[i][j] = sum_a Wq[a][i] * Wk[a][j]
  M[(i0 + ti) * 512 + j0 + tj] = acc;
}

__global__ __launch_bounds__(256, 2) void cca_fused(
    const float* __restrict__ x, const float* __restrict__ Wv,
    const float* __restrict__ M, const float* __restrict__ gammaP,
    float* __restrict__ out) {
  // 65536 B static LDS, phase-unioned:
  //  Phase A: Xs f32[128][33] @0 | Ms f32[32][33] @16896 | Ts f32[128][33] @21120
  //           | Xg f32[128][33] @38016   (end 54912)
  //  Phase B: attn bf16[128][128] @0 | Xsb f32[128][33] @32768
  //           | WvT bf16[32][130] @49664 | Vs bf16[128][128] @32768
  __shared__ __align__(16) unsigned char smem[65536];
  float* Xs = (float*)(smem);
  float* Ms = (float*)(smem + 16896);
  float* Ts = (float*)(smem + 21120);
  float* Xg = (float*)(smem + 38016);
  __hip_bfloat16* attn = (__hip_bfloat16*)(smem);
  float* Xsb = (float*)(smem + 32768);
  __hip_bfloat16* WvT = (__hip_bfloat16*)(smem + 49664);
  __hip_bfloat16* Vs = (__hip_bfloat16*)(smem + 32768);

  const int tid = threadIdx.x;
  const int a = tid >> 4;  // 0..15  (h-group)
  const int b = tid & 15;  // 0..15  (g / j / c group)
  const int col = blockIdx.x;     // 0..1023
  const int bb = col >> 7;        // batch
  const int w = col & 127;
  const float* xcol = x + ((size_t)bb * (HH * WW) + w) * CS;
  float* ocol = out + ((size_t)bb * (HH * WW) + w) * CS;
  const float gamma = gammaP[0];

  // energy tile per thread: e[k][m] = energy[h = a+16k][g = b+16m]
  float e[8][8];
#pragma unroll
  for (int k = 0; k < 8; ++k)
#pragma unroll
    for (int m = 0; m < 8; ++m) e[k][m] = 0.f;

  // ---------------- Phase A: energy = (x_col @ M) @ x_col^T, fp32 ----------------
  for (int jc = 0; jc < 16; ++jc) {
    float tacc[8][2];
#pragma unroll
    for (int k = 0; k < 8; ++k) { tacc[k][0] = 0.f; tacc[k][1] = 0.f; }
    for (int ic = 0; ic < 16; ++ic) {
      __syncthreads();  // protect Xs/Ms (and, at ic==0, Xg/Ts) from prior readers
#pragma unroll
      for (int s = 0; s < 16; ++s) {
        int idx = tid + 256 * s;
        int row = idx >> 5;
        int c2 = idx & 31;
        Xs[row * 33 + c2] = xcol[(size_t)row * HSTRIDE + ic * 32 + c2];
      }
#pragma unroll
      for (int s = 0; s < 4; ++s) {
        int idx = tid + 256 * s;
        int i = idx >> 5;
        int j = idx & 31;
        Ms[i * 33 + j] = M[(ic * 32 + i) * 512 + jc * 32 + j];
      }
      __syncthreads();
      for (int i = 0; i < 32; ++i) {
        float xv[8];
#pragma unroll
        for (int k = 0; k < 8; ++k) xv[k] = Xs[(a + 16 * k) * 33 + i];
        float m0 = Ms[i * 33 + b];
        float m1 = Ms[i * 33 + b + 16];
#pragma unroll
        for (int k = 0; k < 8; ++k) {
          tacc[k][0] = fmaf(xv[k], m0, tacc[k][0]);
          tacc[k][1] = fmaf(xv[k], m1, tacc[k][1]);
        }
      }
    }
    // t[h][j] chunk -> LDS (fp32), stage x[g][j-chunk]
#pragma unroll
    for (int k = 0; k < 8; ++k) {
      Ts[(a + 16 * k) * 33 + b] = tacc[k][0];
      Ts[(a + 16 * k) * 33 + b + 16] = tacc[k][1];
    }
#pragma unroll
    for (int s = 0; s < 16; ++s) {
      int idx = tid + 256 * s;
      int row = idx >> 5;
      int jj = idx & 31;
      Xg[row * 33 + jj] = xcol[(size_t)row * HSTRIDE + jc * 32 + jj];
    }
    __syncthreads();
    for (int jj = 0; jj < 32; ++jj) {
      float tv[8], xv[8];
#pragma unroll
      for (int k = 0; k < 8; ++k) tv[k] = Ts[(a + 16 * k) * 33 + jj];
#pragma unroll
      for (int m = 0; m < 8; ++m) xv[m] = Xg[(b + 16 * m) * 33 + jj];
#pragma unroll
      for (int k = 0; k < 8; ++k)
#pragma unroll
        for (int m = 0; m < 8; ++m) e[k][m] = fmaf(tv[k], xv[m], e[k][m]);
    }
  }

  // ---------------- masked softmax over g (row h), fp32, in regs ----------------
  if (a == b) {
#pragma unroll
    for (int k = 0; k < 8; ++k) e[k][k] = -INFINITY;  // h==g  (a==b && k==m)
  }
  float inv[8];
#pragma unroll
  for (int k = 0; k < 8; ++k) {
    float mx = e[k][0];
#pragma unroll
    for (int m = 1; m < 8; ++m) mx = fmaxf(mx, e[k][m]);
#pragma unroll
    for (int off = 1; off < 16; off <<= 1) mx = fmaxf(mx, __shfl_xor(mx, off, 64));
    float s = 0.f;
#pragma unroll
    for (int m = 0; m < 8; ++m) {
      e[k][m] = __expf(e[k][m] - mx);
      s += e[k][m];
    }
#pragma unroll
    for (int off = 1; off < 16; off <<= 1) s += __shfl_xor(s, off, 64);
    inv[k] = 1.f / s;
  }
  __syncthreads();  // phase A arenas dead; attn overlays Xs
#pragma unroll
  for (int k = 0; k < 8; ++k)
#pragma unroll
    for (int m = 0; m < 8; ++m)
      attn[(a + 16 * k) * 128 + (b + 16 * m)] = __float2bfloat16(e[k][m] * inv[k]);
  __syncthreads();

  // -------- Phase B: v = x_col @ Wv^T (per 128-col chunk), out = attn @ v --------
  for (int cc = 0; cc < 4; ++cc) {
    float vacc[8][8];
#pragma unroll
    for (int k = 0; k < 8; ++k)
#pragma unroll
      for (int m = 0; m < 8; ++m) vacc[k][m] = 0.f;
    for (int ic = 0; ic < 16; ++ic) {
      __syncthreads();  // protect Vs region (prev B2 readers) before restaging
#pragma unroll
      for (int s = 0; s < 16; ++s) {
        int idx = tid + 256 * s;
        int row = idx >> 5;
        int ii = idx & 31;
        Xsb[row * 33 + ii] = xcol[(size_t)row * HSTRIDE + ic * 32 + ii];
      }
#pragma unroll
      for (int s = 0; s < 16; ++s) {
        int idx = tid + 256 * s;
        int c = idx >> 5;   // 0..127
        int i = idx & 31;
        // transposed stage (stride 130 bf16) to avoid 8-way bank conflicts
        WvT[i * 130 + c] = __float2bfloat16(Wv[(cc * 128 + c) * 512 + ic * 32 + i]);
      }
      __syncthreads();
      for (int i = 0; i < 32; ++i) {
        float xv[8], wv[8];
#pragma unroll
        for (int k = 0; k < 8; ++k) xv[k] = Xsb[(a + 16 * k) * 33 + i];
#pragma unroll
        for (int m = 0; m < 8; ++m) wv[m] = __bfloat162float(WvT[i * 130 + b + 16 * m]);
#pragma unroll
        for (int k = 0; k < 8; ++k)
#pragma unroll
          for (int m = 0; m < 8; ++m) vacc[k][m] = fmaf(xv[k], wv[m], vacc[k][m]);
      }
    }
    __syncthreads();  // Xsb/WvT dead; Vs overlays them
#pragma unroll
    for (int k = 0; k < 8; ++k)
#pragma unroll
      for (int m = 0; m < 8; ++m)
        Vs[(a + 16 * k) * 128 + b + 16 * m] = __float2bfloat16(vacc[k][m]);
    __syncthreads();
    float oacc[8][8];
#pragma unroll
    for (int k = 0; k < 8; ++k)
#pragma unroll
      for (int m = 0; m < 8; ++m) oacc[k][m] = 0.f;
    for (int g = 0; g < 128; ++g) {
      float av[8], vv[8];
#pragma unroll
      for (int k = 0; k < 8; ++k) av[k] = __bfloat162float(attn[(a + 16 * k) * 128 + g]);
#pragma unroll
      for (int m = 0; m < 8; ++m) vv[m] = __bfloat162float(Vs[g * 128 + b + 16 * m]);
#pragma unroll
      for (int k = 0; k < 8; ++k)
#pragma unroll
        for (int m = 0; m < 8; ++m) oacc[k][m] = fmaf(av[k], vv[m], oacc[k][m]);
    }
    // epilogue: out = gamma*out_attn + x
#pragma unroll
    for (int k = 0; k < 8; ++k) {
      const int h = a + 16 * k;
      const float* xr = xcol + (size_t)h * HSTRIDE;
      float* orow = ocol + (size_t)h * HSTRIDE;
#pragma unroll
      for (int m = 0; m < 8; ++m) {
        int cg = cc * 128 + b + 16 * m;
        orow[cg] = fmaf(gamma, oacc[k][m], xr[cg]);
      }
    }
  }
}

extern "C" void kernel_launch(void* const* d_in, const int* in_sizes, int n_in,
                              void* d_out, int out_size, void* d_ws, size_t ws_size,
                              hipStream_t stream) {
  const float* x = (const float*)d_in[0];
  const float* Wq = (const float*)d_in[1];
  const float* Wk = (const float*)d_in[2];
  const float* Wv = (const float*)d_in[3];
  const float* gamma = (const float*)d_in[4];
  float* out = (float*)d_out;
  float* M = (float*)d_ws;  // needs 512*512*4 = 1 MB of workspace

  cca_compute_M<<<1024, 256, 0, stream>>>(Wq, Wk, M);
  cca_fused<<<1024, 256, 0, stream>>>(x, Wv, M, gamma, out);
}